// Round 6
// baseline (47.412 us; speedup 1.0000x reference)
//
#include <hip/hip_runtime.h>
#include <math.h>

#define BB 64
#define PP 16
#define FIN 672
#define HH 2048
#define AA 32
#define MM (BB*PP)     // 1024
#define EPSBN 1e-5f
#define NKB 21         // FIN/32

typedef _Float16 f16;
typedef __attribute__((ext_vector_type(8))) _Float16 half8;
typedef __attribute__((ext_vector_type(4))) float floatx4;

// S(h) for the 16-step LIF with constant drive h: spike period m = ceil(-log2(1-1/h)),
// S = sum over spikes q*m<=16 of KC[q*m-1]; exact dyadic values precomputed.
__device__ const float LIF_LUT[18] = {
    0.0f,
    0.93750095367431640625f,   // m=1  (0.9375 + 2^-20)
    0.4583339691162109375f,    // m=2
    0.294643402099609375f,     // m=3
    0.21666717529296875f,      // m=4
    0.1713714599609375f,       // m=5
    0.123016357421875f,        // m=6
    0.11712646484375f,         // m=7
    0.0936279296875f,          // m=8
    0.062255859375f,           // m=9
    0.06201171875f,            // m=10
    0.0615234375f,             // m=11
    0.060546875f,              // m=12
    0.05859375f,               // m=13
    0.0546875f,                // m=14
    0.046875f,                 // m=15
    0.03125f,                  // m=16
    0.0f                       // m>=17: no spike
};

// ---------------------------------------------------------------------------
// Fused prep: blocks [0,448) do A (BN0 + fp16 hi/lo split, MFMA-A frag order);
// blocks [448,1120) do W (fp16 hi/lo split, MFMA-B frag order).
// A frag (mb,kb): lane l holds A[mb*16+(l&15)][kb*32+(l>>4)*8+0..7].
// W frag (nb,kb): lane l holds W[kb*32+(l>>4)*8+0..7][nb*16+(l&15)].
// ---------------------------------------------------------------------------
__global__ __launch_bounds__(256) void k_prep(
    const float* __restrict__ x, const float* __restrict__ w1,
    const float* __restrict__ g0, const float* __restrict__ b0,
    const float* __restrict__ m0, const float* __restrict__ v0,
    f16* __restrict__ Ah, f16* __restrict__ Al,
    f16* __restrict__ Wh, f16* __restrict__ Wl)
{
    __shared__ float sbuf[32 * 65];   // >= 16*97 too
    const int tid = threadIdx.x;
    const int b   = blockIdx.x;

    if (b < 448) {
        // ---- A role: mb = b/7 (16-row group), kc = b%7 (96-k chunk) ----
        const int mb = b / 7;
        const int kc = b % 7;
        #pragma unroll
        for (int i = 0; i < 2; ++i) {
            const int f4 = tid + 256 * i;
            if (f4 < 384) {
                const int row = f4 / 24;
                const int c4  = (f4 % 24) * 4;
                float4 v = *(const float4*)(x + (size_t)(mb * 16 + row) * FIN + kc * 96 + c4);
                sbuf[row * 97 + c4 + 0] = v.x; sbuf[row * 97 + c4 + 1] = v.y;
                sbuf[row * 97 + c4 + 2] = v.z; sbuf[row * 97 + c4 + 3] = v.w;
            }
        }
        __syncthreads();
        if (tid < 192) {
            const int fi   = tid >> 6;          // 0..2 kb-in-chunk
            const int lane = tid & 63;
            const int row  = lane & 15;
            const int koff = fi * 32 + ((lane >> 4) << 3);
            const float a0  = g0[row] / sqrtf(v0[row] + EPSBN);
            const float be0 = b0[row] - m0[row] * a0;
            half8 hi, lo;
            #pragma unroll
            for (int j = 0; j < 8; ++j) {
                const float xn = fmaf(a0, sbuf[row * 97 + koff + j], be0);
                const f16 h = (f16)xn;
                hi[j] = h;
                lo[j] = (f16)(xn - (float)h);
            }
            const int kb = kc * 3 + fi;
            const size_t idx = ((size_t)(mb * NKB + kb) * 64 + lane);
            *(half8*)(Ah + idx * 8) = hi;
            *(half8*)(Al + idx * 8) = lo;
        }
    } else {
        // ---- W role: ng = 64-col group, kb = 32-k block ----
        const int bw = b - 448;
        const int ng = bw & 31;
        const int kb = bw >> 5;     // 0..20
        #pragma unroll
        for (int i = 0; i < 2; ++i) {
            const int f4  = tid + 256 * i;        // 0..511
            const int row = f4 >> 4;
            const int c4  = (f4 & 15) * 4;
            float4 v = *(const float4*)(w1 + (size_t)(kb * 32 + row) * HH + ng * 64 + c4);
            sbuf[row * 65 + c4 + 0] = v.x; sbuf[row * 65 + c4 + 1] = v.y;
            sbuf[row * 65 + c4 + 2] = v.z; sbuf[row * 65 + c4 + 3] = v.w;
        }
        __syncthreads();
        const int fi   = tid >> 6;     // 0..3
        const int lane = tid & 63;
        const int col  = fi * 16 + (lane & 15);
        const int kr   = (lane >> 4) << 3;
        half8 hi, lo;
        #pragma unroll
        for (int j = 0; j < 8; ++j) {
            const float wv = sbuf[(kr + j) * 65 + col];
            const f16 h = (f16)wv;
            hi[j] = h;
            lo[j] = (f16)(wv - (float)h);
        }
        const int nb = ng * 4 + fi;
        const size_t idx = ((size_t)(nb * NKB + kb) * 64 + lane);
        *(half8*)(Wh + idx * 8) = hi;
        *(half8*)(Wl + idx * 8) = lo;
    }
}

// ---------------------------------------------------------------------------
// GEMM1 split-K x2 via MFMA fp16-split (hh + hl + lh). 64-thr blocks (1 wave),
// wave tile 32x32 (2x2 frags), grid 4096 -> 16 blocks/CU = 4 waves/SIMD.
// XCD n-stripe swizzle: blockIdx%8 = XCD owns 256 cols of W (stripe 0.69MB)
// + full A (2.75MB) -> fits 4MB L2; all steady-state loads are L2 hits.
// Writes fp32 partials: part[half][row][col].
// ---------------------------------------------------------------------------
__global__ __launch_bounds__(64, 4) void k_gemm1_splitk(
    const f16* __restrict__ Ah, const f16* __restrict__ Al,
    const f16* __restrict__ Wh, const f16* __restrict__ Wl,
    float* __restrict__ part)   // part0; part1 = part + MM*HH
{
    const int lane = threadIdx.x;
    const int b    = blockIdx.x;        // 0..4095
    const int xcd  = b & 7;
    const int idx  = b >> 3;            // 0..511
    const int nt   = xcd * 8 + (idx & 7);   // 0..63 : 32-col tile
    const int mt   = (idx >> 3) & 31;       // 0..31 : 32-row tile
    const int half = idx >> 8;              // 0..1 : K-half
    const int kb0  = half ? 11 : 0;
    const int kbN  = half ? 21 : 11;
    float* pt = part + (size_t)half * MM * HH;

    const int mb0 = mt * 2;
    const int nb0 = nt * 2;

    int baseA[2], baseB[2];
    #pragma unroll
    for (int m = 0; m < 2; ++m) baseA[m] = (mb0 + m) * NKB * 64 + lane;
    #pragma unroll
    for (int n = 0; n < 2; ++n) baseB[n] = (nb0 + n) * NKB * 64 + lane;

    const half8* pAh = (const half8*)Ah;
    const half8* pAl = (const half8*)Al;
    const half8* pWh = (const half8*)Wh;
    const half8* pWl = (const half8*)Wl;

    floatx4 acc[2][2];
    #pragma unroll
    for (int m = 0; m < 2; ++m)
        #pragma unroll
        for (int n = 0; n < 2; ++n) acc[m][n] = (floatx4){0.f,0.f,0.f,0.f};

    half8 a0h[2], a0l[2], b0h[2], b0l[2];
    half8 a1h[2], a1l[2], b1h[2], b1l[2];

#define LOADK(kb, ah, al, bh, bl) do {                                        \
    _Pragma("unroll") for (int m_ = 0; m_ < 2; ++m_) {                        \
        ah[m_] = pAh[baseA[m_] + (kb) * 64];                                  \
        al[m_] = pAl[baseA[m_] + (kb) * 64]; }                                \
    _Pragma("unroll") for (int n_ = 0; n_ < 2; ++n_) {                        \
        bh[n_] = pWh[baseB[n_] + (kb) * 64];                                  \
        bl[n_] = pWl[baseB[n_] + (kb) * 64]; }                                \
} while (0)

#define COMPUTE(ah, al, bh, bl) do {                                          \
    _Pragma("unroll") for (int m_ = 0; m_ < 2; ++m_)                          \
    _Pragma("unroll") for (int n_ = 0; n_ < 2; ++n_)                          \
        acc[m_][n_] = __builtin_amdgcn_mfma_f32_16x16x32_f16(                 \
            ah[m_], bh[n_], acc[m_][n_], 0, 0, 0);                            \
    _Pragma("unroll") for (int m_ = 0; m_ < 2; ++m_)                          \
    _Pragma("unroll") for (int n_ = 0; n_ < 2; ++n_)                          \
        acc[m_][n_] = __builtin_amdgcn_mfma_f32_16x16x32_f16(                 \
            ah[m_], bl[n_], acc[m_][n_], 0, 0, 0);                            \
    _Pragma("unroll") for (int m_ = 0; m_ < 2; ++m_)                          \
    _Pragma("unroll") for (int n_ = 0; n_ < 2; ++n_)                          \
        acc[m_][n_] = __builtin_amdgcn_mfma_f32_16x16x32_f16(                 \
            al[m_], bh[n_], acc[m_][n_], 0, 0, 0);                            \
} while (0)

    LOADK(kb0, a0h, a0l, b0h, b0l);
    int kb;
    for (kb = kb0; kb + 2 <= kbN; kb += 2) {
        LOADK(kb + 1, a1h, a1l, b1h, b1l);
        COMPUTE(a0h, a0l, b0h, b0l);
        if (kb + 2 < kbN) LOADK(kb + 2, a0h, a0l, b0h, b0l);
        COMPUTE(a1h, a1l, b1h, b1l);
    }
    if (kb < kbN) COMPUTE(a0h, a0l, b0h, b0l);   // odd kb count
#undef LOADK
#undef COMPUTE

    const int r4 = (lane >> 4) << 2;
    #pragma unroll
    for (int n = 0; n < 2; ++n) {
        const int col = (nb0 + n) * 16 + (lane & 15);
        #pragma unroll
        for (int m = 0; m < 2; ++m) {
            const int rowbase = (mb0 + m) * 16 + r4;
            #pragma unroll
            for (int j = 0; j < 4; ++j)
                __builtin_nontemporal_store(acc[m][n][j],
                    pt + (size_t)(rowbase + j) * HH + col);
        }
    }
}

// ---------------------------------------------------------------------------
// GEMM2 + fused split-K combine + bias1/BN1/LIF.
// Grid (128 row-groups of 8) x (8 k-chunks of 256). Phase 1: each thread
// computes spike-sums s for (8 rows x its column h) from part0+part1 -> LDS.
// Phase 2: 256-deep FMA with LDS-staged w2 chunk.
// ---------------------------------------------------------------------------
__global__ __launch_bounds__(256) void k_gemm2_lif(
    const float* __restrict__ part01,   // [2][1024][2048] fp32
    const float* __restrict__ w2, const float* __restrict__ bias1,
    const float* __restrict__ g1, const float* __restrict__ b1,
    const float* __restrict__ m1, const float* __restrict__ v1,
    float* __restrict__ part2)
{
    __shared__ float w2s[8192];     // 256 k x 32 cols
    __shared__ float s_l[8][257];
    __shared__ float lut[18];
    const int tid = threadIdx.x;
    const int rg  = blockIdx.x;     // 0..127
    const int kc  = blockIdx.y;     // 0..7

    if (tid < 18) lut[tid] = LIF_LUT[tid];
    const float4* src = (const float4*)(w2 + (size_t)kc * 8192);
    #pragma unroll
    for (int i = tid; i < 2048; i += 256) ((float4*)w2s)[i] = src[i];
    __syncthreads();

    // phase 1: spikes for this block's 8 rows x 256 h-columns
    {
        const int hc  = kc * 256 + tid;        // this thread's h column
        const float bs = bias1[hc];
        const float H16 = (float)(65536.0 / 65535.0);
        #pragma unroll
        for (int r = 0; r < 8; ++r) {
            const int row = rg * 8 + r;
            const int p   = row & 15;
            const float a1  = g1[p] / sqrtf(v1[p] + EPSBN);
            const float be1 = b1[p] - m1[p] * a1;
            const float tot = part01[(size_t)row * HH + hc]
                            + part01[(size_t)(MM + row) * HH + hc];
            const float h = fmaf(a1, tot + bs, be1);
            float s = 0.f;
            if (h >= H16) {
                const float rr = 1.f - __builtin_amdgcn_rcpf(h);
                int mi = (int)ceilf(-__log2f(rr));
                mi = mi < 1 ? 1 : (mi > 17 ? 17 : mi);
                s = lut[mi];
            }
            s_l[r][tid] = s;
        }
    }
    __syncthreads();

    // phase 2: y partial = sum_j s * w2
    const int rw  = tid >> 5;
    const int col = tid & 31;
    float acc0 = 0.f, acc1 = 0.f;
    #pragma unroll 8
    for (int j = 0; j < 256; j += 2) {
        acc0 = fmaf(s_l[rw][j + 0], w2s[(j + 0) * 32 + col], acc0);
        acc1 = fmaf(s_l[rw][j + 1], w2s[(j + 1) * 32 + col], acc1);
    }
    part2[((size_t)kc * MM + rg * 8 + rw) * AA + col] = acc0 + acc1;
}

// ---------------------------------------------------------------------------
// Finish: reduce 8 partials + folded BN2 / bias2 / ns-LIF-mean + tanh*2.
// ---------------------------------------------------------------------------
__global__ __launch_bounds__(256) void k_finish(
    const float* __restrict__ part2, const float* __restrict__ bias2,
    const float* __restrict__ g2, const float* __restrict__ b2,
    const float* __restrict__ m2, const float* __restrict__ v2,
    float* __restrict__ out)
{
    const int i   = blockIdx.x * 256 + threadIdx.x;
    const int col = i & 31;
    const int row = i >> 5;
    const int p   = row & 15;
    float acc = 0.f;
    #pragma unroll
    for (int s = 0; s < 8; ++s) acc += part2[(size_t)s * MM * AA + i];
    const float a2   = g2[p] / sqrtf(v2[p] + EPSBN);
    const float be2  = b2[p] - m2[p] * a2;
    const float Csum = 0.9375f + 0x1p-20f;
    const float val  = fmaf(a2, acc + Csum * bias2[col], Csum * be2);
    out[i] = 2.0f * tanhf(val);
}

// ---------------------------------------------------------------------------
// Fallback path (only if ws too small): fp32 LDS GEMM1 -> f16 S -> gemm2.
// ---------------------------------------------------------------------------
__global__ __launch_bounds__(256) void k_gemm1_fp32(
    const float* __restrict__ x, const float* __restrict__ w1,
    const float* __restrict__ bias1,
    const float* __restrict__ g0, const float* __restrict__ b0,
    const float* __restrict__ m0, const float* __restrict__ v0,
    const float* __restrict__ g1, const float* __restrict__ b1,
    const float* __restrict__ m1, const float* __restrict__ v1,
    f16* __restrict__ S)
{
    __shared__ float As[16][36];
    __shared__ float Bs[16][68];

    const int tid = threadIdx.x;
    const int bx  = blockIdx.x;
    const int by  = blockIdx.y;

    const int ar   = tid & 31;
    const int ak   = (tid >> 5) << 1;
    const int grow = by * 32 + ar;
    const int pA   = grow & 15;
    const float a0  = g0[pA] / sqrtf(v0[pA] + EPSBN);
    const float be0 = b0[pA] - m0[pA] * a0;
    const float* xrow = x + (size_t)grow * FIN;

    const int brk = tid >> 4;
    const int bcc = (tid & 15) << 2;
    const float* wp = w1 + (size_t)brk * HH + bx * 64 + bcc;

    const int tx = tid & 15;
    const int ty = tid >> 4;

    float acc[2][4];
    #pragma unroll
    for (int i = 0; i < 2; ++i)
        #pragma unroll
        for (int j = 0; j < 4; ++j) acc[i][j] = 0.f;

    float2 aPre = *(const float2*)(xrow + ak);
    float4 bPre = *(const float4*)(wp);

    for (int kt = 0; kt < FIN; kt += 16) {
        As[ak + 0][ar] = fmaf(a0, aPre.x, be0);
        As[ak + 1][ar] = fmaf(a0, aPre.y, be0);
        *(float4*)&Bs[brk][bcc] = bPre;
        __syncthreads();
        if (kt + 16 < FIN) {
            aPre = *(const float2*)(xrow + kt + 16 + ak);
            bPre = *(const float4*)(wp + (size_t)(kt + 16) * HH);
        }
        #pragma unroll
        for (int k = 0; k < 16; ++k) {
            float2 a2 = *(const float2*)&As[k][ty << 1];
            float4 b4 = *(const float4*)&Bs[k][tx << 2];
            float aa[2] = {a2.x, a2.y};
            float bb[4] = {b4.x, b4.y, b4.z, b4.w};
            #pragma unroll
            for (int i = 0; i < 2; ++i)
                #pragma unroll
                for (int j = 0; j < 4; ++j)
                    acc[i][j] = fmaf(aa[i], bb[j], acc[i][j]);
        }
        __syncthreads();
    }

    const float KC[16] = {
        (1.0f-0x1p-16f)*0.0625f,(1.0f-0x1p-15f)*0.0625f,(1.0f-0x1p-14f)*0.0625f,(1.0f-0x1p-13f)*0.0625f,
        (1.0f-0x1p-12f)*0.0625f,(1.0f-0x1p-11f)*0.0625f,(1.0f-0x1p-10f)*0.0625f,(1.0f-0x1p-9f)*0.0625f,
        (1.0f-0x1p-8f)*0.0625f,(1.0f-0x1p-7f)*0.0625f,(1.0f-0x1p-6f)*0.0625f,(1.0f-0x1p-5f)*0.0625f,
        (1.0f-0x1p-4f)*0.0625f,(1.0f-0x1p-3f)*0.0625f,(1.0f-0x1p-2f)*0.0625f,(1.0f-0x1p-1f)*0.0625f
    };

    const int col0 = bx * 64 + (tx << 2);
    float4 bias4 = *(const float4*)(bias1 + col0);
    const float bias_arr[4] = {bias4.x, bias4.y, bias4.z, bias4.w};

    #pragma unroll
    for (int i = 0; i < 2; ++i) {
        const int r = by * 32 + (ty << 1) + i;
        const int p = r & 15;
        const float a1  = g1[p] / sqrtf(v1[p] + EPSBN);
        const float be1 = b1[p] - m1[p] * a1;
        #pragma unroll
        for (int j = 0; j < 4; ++j) {
            const float h = fmaf(a1, acc[i][j] + bias_arr[j], be1);
            float v = 0.f, s = 0.f;
            #pragma unroll
            for (int t = 0; t < 16; ++t) {
                v = v + (h - v) * 0.5f;
                if (v >= 1.0f) { s += KC[t]; v = 0.f; }
            }
            S[(size_t)r * HH + col0 + j] = (f16)s;
        }
    }
}

__global__ __launch_bounds__(256) void k_gemm2_part_f16(
    const f16* __restrict__ S, const float* __restrict__ w2,
    float* __restrict__ part2)
{
    __shared__ float w2s[8192];
    const int tid = threadIdx.x;
    const int rg  = blockIdx.x;
    const int kc  = blockIdx.y;

    const float4* src = (const float4*)(w2 + (size_t)kc * 8192);
    #pragma unroll
    for (int i = tid; i < 2048; i += 256) ((float4*)w2s)[i] = src[i];
    __syncthreads();

    const int rw  = tid >> 5;
    const int col = tid & 31;
    const int row = rg * 8 + rw;
    const f16* Sp = S + (size_t)row * HH + kc * 256;

    float acc0 = 0.f, acc1 = 0.f;
    #pragma unroll 4
    for (int j = 0; j < 256; j += 8) {
        half8 s8 = *(const half8*)(Sp + j);
        acc0 = fmaf((float)s8[0], w2s[(j + 0) * 32 + col], acc0);
        acc1 = fmaf((float)s8[1], w2s[(j + 1) * 32 + col], acc1);
        acc0 = fmaf((float)s8[2], w2s[(j + 2) * 32 + col], acc0);
        acc1 = fmaf((float)s8[3], w2s[(j + 3) * 32 + col], acc1);
        acc0 = fmaf((float)s8[4], w2s[(j + 4) * 32 + col], acc0);
        acc1 = fmaf((float)s8[5], w2s[(j + 5) * 32 + col], acc1);
        acc0 = fmaf((float)s8[6], w2s[(j + 6) * 32 + col], acc0);
        acc1 = fmaf((float)s8[7], w2s[(j + 7) * 32 + col], acc1);
    }
    part2[((size_t)kc * MM + row) * AA + col] = acc0 + acc1;
}

extern "C" void kernel_launch(void* const* d_in, const int* in_sizes, int n_in,
                              void* d_out, int out_size, void* d_ws, size_t ws_size,
                              hipStream_t stream) {
    (void)in_sizes; (void)n_in; (void)out_size;
    const float* x     = (const float*)d_in[0];
    const float* w1    = (const float*)d_in[1];
    const float* bias1 = (const float*)d_in[2];
    const float* w2    = (const float*)d_in[3];
    const float* bias2 = (const float*)d_in[4];
    const float* g0 = (const float*)d_in[5];
    const float* b0 = (const float*)d_in[6];
    const float* m0 = (const float*)d_in[7];
    const float* v0 = (const float*)d_in[8];
    const float* g1 = (const float*)d_in[9];
    const float* b1 = (const float*)d_in[10];
    const float* m1 = (const float*)d_in[11];
    const float* v1 = (const float*)d_in[12];
    const float* g2 = (const float*)d_in[13];
    const float* b2 = (const float*)d_in[14];
    const float* m2 = (const float*)d_in[15];
    const float* v2 = (const float*)d_in[16];
    float* out = (float*)d_out;

    // ws: Ah 1.31M | Al 1.31M | Wh 2.62M | Wl 2.62M | part01 16M | part2 1M
    const size_t offAl   = 1376256;
    const size_t offWh   = 2752512;
    const size_t offWl   = 5505024;
    const size_t offP01  = 8257536;
    const size_t offP2   = offP01 + 2u * MM * HH * sizeof(float);  // +16 MB
    const size_t needed  = offP2 + (size_t)8 * MM * AA * sizeof(float);

    if (ws_size >= needed) {
        f16* Ah = (f16*)d_ws;
        f16* Al = (f16*)((char*)d_ws + offAl);
        f16* Wh = (f16*)((char*)d_ws + offWh);
        f16* Wl = (f16*)((char*)d_ws + offWl);
        float* part01 = (float*)((char*)d_ws + offP01);
        float* part2  = (float*)((char*)d_ws + offP2);

        k_prep<<<1120, 256, 0, stream>>>(x, w1, g0, b0, m0, v0, Ah, Al, Wh, Wl);
        k_gemm1_splitk<<<4096, 64, 0, stream>>>(Ah, Al, Wh, Wl, part01);
        k_gemm2_lif<<<dim3(128, 8), 256, 0, stream>>>(part01, w2, bias1,
                                                      g1, b1, m1, v1, part2);
        k_finish<<<dim3(128), 256, 0, stream>>>(part2, bias2, g2, b2, m2, v2, out);
    } else {
        f16* S      = (f16*)d_ws;
        float* part2 = (float*)((char*)d_ws + (size_t)MM * HH * sizeof(f16));
        k_gemm1_fp32<<<dim3(32, 32), 256, 0, stream>>>(x, w1, bias1,
                                                       g0, b0, m0, v0,
                                                       g1, b1, m1, v1, S);
        k_gemm2_part_f16<<<dim3(128, 8), 256, 0, stream>>>(S, w2, part2);
        k_finish<<<dim3(128), 256, 0, stream>>>(part2, bias2, g2, b2, m2, v2, out);
    }
}